// Round 6
// baseline (301.531 us; speedup 1.0000x reference)
//
#include <hip/hip_runtime.h>
#include <hip/hip_bf16.h>
#include <cstdint>

#define B_   2
#define S_   2048
#define D_   1024
#define H_   16
#define DPH_ 64
#define NT_  (S_ / 64)

typedef float f32x4 __attribute__((ext_vector_type(4)));
typedef short bf16x8 __attribute__((ext_vector_type(8)));
typedef unsigned short u16;

static const size_t NE = (size_t)B_ * S_ * D_;   // 4,194,304 elements
static const size_t DD = (size_t)D_ * D_;

__device__ __forceinline__ u16 f2bf(float f) {
  union { float f; unsigned u; } cv; cv.f = f;
  unsigned u = cv.u;
  return (u16)((u + 0x7fffu + ((u >> 16) & 1u)) >> 16);
}

__device__ __forceinline__ unsigned cvtpk(float a, float b) {
  unsigned r;
  asm("v_cvt_pk_bf16_f32 %0, %1, %2" : "=v"(r) : "v"(a), "v"(b));
  return r;
}

__device__ __forceinline__ void gld16(const void* g, void* l) {
  __builtin_amdgcn_global_load_lds((const __attribute__((address_space(1))) unsigned int*)g,
                                   (__attribute__((address_space(3))) unsigned int*)l, 16, 0, 0);
}

// ---------------- mask format detection (512KB scan, wave-reduced, plain stores) ----------------
__global__ __launch_bounds__(256) void detect_mask_fmt(const uint4* __restrict__ m,
                                                       unsigned int* __restrict__ flags) {
  int i = blockIdx.x * 256 + threadIdx.x;
  uint4 v = m[i];
  int a = (v.x > 1u) | (v.y > 1u) | (v.z > 1u) | (v.w > 1u);
  int bb = ((v.x != 0u && v.x != 0x3f800000u) | (v.y != 0u && v.y != 0x3f800000u) |
            (v.z != 0u && v.z != 0x3f800000u) | (v.w != 0u && v.w != 0x3f800000u));
  int anyA = __any(a), anyB = __any(bb);
  if ((threadIdx.x & 63) == 0) {
    if (anyA) flags[0] = 1u;
    if (anyB) flags[1] = 1u;
  }
}

// ---------------- mask -> bitmask: M1[b][q][w] u64, bit k = disallowed ----------------
__device__ __forceinline__ unsigned nz4(unsigned w) {
  unsigned r = 0;
  if (w & 0x000000ffu) r |= 1u;
  if (w & 0x0000ff00u) r |= 2u;
  if (w & 0x00ff0000u) r |= 4u;
  if (w & 0xff000000u) r |= 8u;
  return r;
}

__global__ __launch_bounds__(256) void prep_bits(const void* __restrict__ src,
                                                 const unsigned int* __restrict__ flags,
                                                 unsigned long long* __restrict__ dst) {
  int i = blockIdx.x * 256 + threadIdx.x;
  unsigned long long w = 0;
  bool fourB = (flags[0] == 0u) || (flags[1] == 0u);
  if (fourB) {
    const uint4* p = (const uint4*)src + (size_t)i * 16;
#pragma unroll
    for (int j = 0; j < 16; ++j) {
      uint4 v = p[j];
      unsigned bits = (v.x ? 1u : 0u) | (v.y ? 2u : 0u) | (v.z ? 4u : 0u) | (v.w ? 8u : 0u);
      w |= (unsigned long long)bits << (j * 4);
    }
  } else {
    const uint4* p = (const uint4*)src + (size_t)i * 4;
#pragma unroll
    for (int j = 0; j < 4; ++j) {
      uint4 v = p[j];
      w |= (unsigned long long)nz4(v.x) << (j * 16 + 0);
      w |= (unsigned long long)nz4(v.y) << (j * 16 + 4);
      w |= (unsigned long long)nz4(v.z) << (j * 16 + 8);
      w |= (unsigned long long)nz4(v.w) << (j * 16 + 12);
    }
  }
  dst[i] = w;
}

// ---------------- weight transpose + convert: WT[n][k] = bf16(W[k][n]) ----------------
__global__ __launch_bounds__(256) void cvt_w(const float* __restrict__ Wq, const float* __restrict__ Wk,
                                             const float* __restrict__ Wv, const float* __restrict__ Wo,
                                             u16* __restrict__ WT) {
  int idx2 = blockIdx.x;                        // [0,2048)
  int mat = idx2 >> 9;
  const float* W = (mat == 0) ? Wq : (mat == 1) ? Wk : (mat == 2) ? Wv : Wo;
  u16* O = WT + (size_t)mat * DD;
  int t = (idx2 & 511) * 256 + threadIdx.x;     // [0,131072)
  int n = t & 1023, k8 = (t >> 10) << 3;
  bf16x8 o;
#pragma unroll
  for (int j = 0; j < 8; ++j) o[j] = (short)f2bf(W[(size_t)(k8 + j) * D_ + n]);
  *(bf16x8*)(O + (size_t)n * D_ + k8) = o;
}

// ---------------- bf16 MFMA GEMM: C = scale*(A @ WT^T + bias) ----------------
// AF32=1: A is f32 [M][1024] (in-register cvt to bf16); AF32=0: A is bf16.
// mode 0: bf16 out; 1: f32 out; 2: bf16 VT[b][h][dn][s] via LDS transpose.
struct GArgs {
  const void* A[3]; const u16* W[3]; const float* bias[3];
  void* C[3]; float scale[3]; int mode[3];
};

template <int AF32>
__global__ __launch_bounds__(256, 3) void gemm_bf16(GArgs ga) {
  __shared__ unsigned char smem[49152];
  constexpr int ABUF = AF32 ? 16384 : 8192;     // per-buffer A bytes
  const int z = blockIdx.z;
  const u16* WT = ga.W[z]; const float* bias = ga.bias[z];
  void* Cout = ga.C[z]; const float scale = ga.scale[z]; const int mode = ga.mode[z];

  const int tid = threadIdx.x, wv = tid >> 6, lane = tid & 63;
  const int hi = lane >> 4, lo = lane & 15;
  const int wm = wv >> 1, wn = wv & 1;
  const int m0 = blockIdx.y * 128, n0 = blockIdx.x * 128;
  const char* ag = (const char*)ga.A[z] + (size_t)m0 * (AF32 ? 4096 : 2048);
  const char* bg = (const char*)WT + (size_t)n0 * 2048;
  unsigned char* sB0 = smem + 2 * ABUF;

  f32x4 acc[4][4];
#pragma unroll
  for (int i = 0; i < 4; ++i)
#pragma unroll
    for (int j = 0; j < 4; ++j) acc[i][j] = (f32x4){0.f, 0.f, 0.f, 0.f};

  // stage A tile (128 rows x 32k) — f32: 16KB, 16 chunks; bf16: 8KB, 8 chunks. XOR-swz source.
  auto stageA = [&](unsigned char* dst, int kt) {
    if constexpr (AF32) {
#pragma unroll
      for (int p = 0; p < 4; ++p) {
        int cid = p * 4 + wv;
        int slot = cid * 64 + lane;
        int r = slot >> 3, c = slot & 7;
        gld16(ag + (size_t)r * 4096 + kt * 128 + ((c ^ (r & 7)) * 16), dst + cid * 1024);
      }
    } else {
#pragma unroll
      for (int p = 0; p < 2; ++p) {
        int cid = p * 4 + wv;
        int slot = cid * 64 + lane;
        int r = slot >> 2, c = slot & 3;
        gld16(ag + (size_t)r * 2048 + kt * 64 + ((c ^ (r & 3)) * 16), dst + cid * 1024);
      }
    }
  };
  auto stageB = [&](unsigned char* dst, int kt) {
#pragma unroll
    for (int p = 0; p < 2; ++p) {
      int cid = p * 4 + wv;
      int slot = cid * 64 + lane;
      int r = slot >> 2, c = slot & 3;
      gld16(bg + (size_t)r * 2048 + kt * 64 + ((c ^ (r & 3)) * 16), dst + cid * 1024);
    }
  };

  stageA(smem, 0);
  stageB(sB0, 0);

  for (int kt = 0; kt < 32; ++kt) {
    int cur = kt & 1;
    unsigned char* sA = smem + cur * ABUF;
    unsigned char* sB = sB0 + cur * 8192;
    if (kt < 31) {
      stageA(smem + (cur ^ 1) * ABUF, kt + 1);
      stageB(sB0 + (cur ^ 1) * 8192, kt + 1);
      if constexpr (AF32) asm volatile("s_waitcnt vmcnt(6)" ::: "memory");
      else                asm volatile("s_waitcnt vmcnt(4)" ::: "memory");
    } else {
      asm volatile("s_waitcnt vmcnt(0)" ::: "memory");
    }
    __builtin_amdgcn_s_barrier();
    __builtin_amdgcn_sched_barrier(0);

    bf16x8 af[4], bf[4];
#pragma unroll
    for (int i = 0; i < 4; ++i) {
      int mr = 64 * wm + 16 * i + lo;
      if constexpr (AF32) {
        int s7 = mr & 7;
        f32x4 A0 = *(const f32x4*)(sA + mr * 128 + (((2 * hi) ^ s7) * 16));
        f32x4 A1 = *(const f32x4*)(sA + mr * 128 + (((2 * hi + 1) ^ s7) * 16));
        union { uint4 u; bf16x8 v; } cvu;
        cvu.u = make_uint4(cvtpk(A0[0], A0[1]), cvtpk(A0[2], A0[3]),
                           cvtpk(A1[0], A1[1]), cvtpk(A1[2], A1[3]));
        af[i] = cvu.v;
      } else {
        af[i] = *(const bf16x8*)(sA + mr * 64 + ((hi ^ (mr & 3)) * 16));
      }
      int nr = 64 * wn + 16 * i + lo;
      bf[i] = *(const bf16x8*)(sB + nr * 64 + ((hi ^ (nr & 3)) * 16));
    }
#pragma unroll
    for (int i = 0; i < 4; ++i)
#pragma unroll
      for (int j = 0; j < 4; ++j)
        acc[i][j] = __builtin_amdgcn_mfma_f32_16x16x32_bf16(af[i], bf[j], acc[i][j], 0, 0, 0);

    __builtin_amdgcn_sched_barrier(0);
    __builtin_amdgcn_s_barrier();
  }

  float bv[4];
#pragma unroll
  for (int j = 0; j < 4; ++j) bv[j] = bias[n0 + 64 * wn + 16 * j + lo];

  if (mode <= 1) {
#pragma unroll
    for (int i = 0; i < 4; ++i)
#pragma unroll
      for (int r = 0; r < 4; ++r) {
        int m = m0 + 64 * wm + 16 * i + 4 * hi + r;
#pragma unroll
        for (int j = 0; j < 4; ++j) {
          int n = n0 + 64 * wn + 16 * j + lo;
          float val = (acc[i][j][r] + bv[j]) * scale;
          if (mode == 0) ((u16*)Cout)[(size_t)m * D_ + n] = f2bf(val);
          else           ((float*)Cout)[(size_t)m * D_ + n] = val;
        }
      }
  } else {
    // V: transpose 128x128 tile through LDS, write VT[b][h][dn][s] coalesced
    __syncthreads();
#pragma unroll
    for (int i = 0; i < 4; ++i) {
      int mb2 = 64 * wm + 16 * i + 4 * hi;
#pragma unroll
      for (int j = 0; j < 4; ++j) {
        int n = 64 * wn + 16 * j + lo;
        unsigned w0 = (unsigned)f2bf(acc[i][j][0] + bv[j]) | ((unsigned)f2bf(acc[i][j][1] + bv[j]) << 16);
        unsigned w1 = (unsigned)f2bf(acc[i][j][2] + bv[j]) | ((unsigned)f2bf(acc[i][j][3] + bv[j]) << 16);
        unsigned byteoff = n * 256 + ((2 * mb2) ^ ((n & 7) << 5));
        *(uint2*)(smem + byteoff) = make_uint2(w0, w1);
      }
    }
    __syncthreads();
    int nl = tid >> 1, half = tid & 1;
    unsigned ob[32];
#pragma unroll
    for (int s = 0; s < 16; ++s) {
      unsigned byteoff = nl * 256 + ((128 * half + 8 * s) ^ ((nl & 7) << 5));
      uint2 vv = *(const uint2*)(smem + byteoff);
      ob[2 * s] = vv.x; ob[2 * s + 1] = vv.y;
    }
    int bb = blockIdx.y >> 4;
    int habs = blockIdx.x * 2 + (nl >> 6);
    int dn = nl & 63;
    size_t sg = (size_t)(blockIdx.y & 15) * 128 + half * 64;
    u16* outp = (u16*)Cout + ((size_t)(bb * H_ + habs) * 64 + dn) * 2048 + sg;
#pragma unroll
    for (int c2 = 0; c2 < 8; ++c2)
      *(uint4*)(outp + c2 * 8) = *(uint4*)&ob[4 * c2];
  }
}

// ---------------- MFMA flash attention: max-free softmax, compile-time dbuf ----------------
// 4 waves x 32 q-rows. scores via mfma(K,Q): lane owns q-rows (lo, 16+lo) of its wave.
// softmax: p = exp2(min(sc,88)) (shift-invariant, clamp prevents overflow); l-reduce deferred.
// PV via mfma(V^T,P): acc is ctx^T (d per reg, q per lane). CTX may alias Qb.
__global__ __launch_bounds__(256, 3) void attn_mfma3(const u16* __restrict__ Qb,
                                                     const u16* __restrict__ Kb,
                                                     const u16* __restrict__ VT,
                                                     const unsigned long long* __restrict__ M1,
                                                     u16* __restrict__ CTX) {
  __shared__ unsigned char sK[2][8192];
  __shared__ unsigned char sV[2][8192];
  __shared__ unsigned char sP[4][4096];
  const int tid = threadIdx.x, wv = tid >> 6, lane = tid & 63;
  const int hi = lane >> 4, lo = lane & 15;
  const int b = blockIdx.y >> 4, h = blockIdx.y & (H_ - 1);
  const int q0 = blockIdx.x * 128;
  const char* kg = (const char*)(Kb + (size_t)b * S_ * D_ + h * 64);
  const char* vg = (const char*)(VT + ((size_t)(b * H_ + h) * 64) * S_);
  unsigned* sPw = (unsigned*)sP[wv];

  const u16* qr0 = Qb + ((size_t)b * S_ + q0 + 32 * wv + lo) * D_ + h * 64;
  bf16x8 qa[2][2];
  qa[0][0] = *(const bf16x8*)(qr0 + 8 * hi);
  qa[0][1] = *(const bf16x8*)(qr0 + 32 + 8 * hi);
  qa[1][0] = *(const bf16x8*)(qr0 + (size_t)16 * D_ + 8 * hi);
  qa[1][1] = *(const bf16x8*)(qr0 + (size_t)16 * D_ + 32 + 8 * hi);

  auto stage8 = [&](unsigned char* dst, const char* srcbase, size_t rs) {
#pragma unroll
    for (int p = 0; p < 2; ++p) {
      int cid = p * 4 + wv;
      int slot = cid * 64 + lane;
      int r = slot >> 3, c = slot & 7;
      gld16(srcbase + (size_t)r * rs + ((c ^ (r & 7)) * 16), dst + cid * 1024);
    }
  };

  stage8(sK[0], kg, 2048);
  stage8(sV[0], vg, 4096);

  f32x4 acc[2][4];
#pragma unroll
  for (int hf = 0; hf < 2; ++hf)
#pragma unroll
    for (int i = 0; i < 4; ++i) acc[hf][i] = (f32x4){0.f, 0.f, 0.f, 0.f};
  float lrowp[2] = {0.f, 0.f};                  // per-lane partial denominators
  const unsigned long long* mrp = M1 + ((size_t)b * S_ + q0 + 32 * wv + lo) * NT_;

#define ATTN_STEP(CUR, KT)                                                             \
  {                                                                                    \
    if ((KT) < NT_ - 1) {                                                              \
      stage8(sK[(CUR) ^ 1], kg + (size_t)((KT) + 1) * 64 * 2048, 2048);                \
      stage8(sV[(CUR) ^ 1], vg + (size_t)((KT) + 1) * 128, 4096);                      \
      asm volatile("s_waitcnt vmcnt(4)" ::: "memory");                                 \
    } else {                                                                           \
      asm volatile("s_waitcnt vmcnt(0)" ::: "memory");                                 \
    }                                                                                  \
    __builtin_amdgcn_s_barrier();                                                      \
    __builtin_amdgcn_sched_barrier(0);                                                 \
    unsigned long long mwh0 = mrp[(KT)] >> (unsigned)(4 * hi);                         \
    unsigned long long mwh1 = mrp[(size_t)16 * NT_ + (KT)] >> (unsigned)(4 * hi);      \
    f32x4 sc[2][4];                                                                    \
    __builtin_amdgcn_s_setprio(1);                                                     \
    _Pragma("unroll")                                                                  \
    for (int nf = 0; nf < 4; ++nf) {                                                   \
      int key = 16 * nf + lo;                                                          \
      bf16x8 kb0 = *(const bf16x8*)(sK[(CUR)] + key * 128 + (((0 + hi) ^ (key & 7)) * 16)); \
      bf16x8 kb1 = *(const bf16x8*)(sK[(CUR)] + key * 128 + (((4 + hi) ^ (key & 7)) * 16)); \
      f32x4 z0 = (f32x4){0.f, 0.f, 0.f, 0.f};                                          \
      f32x4 z1 = (f32x4){0.f, 0.f, 0.f, 0.f};                                          \
      z0 = __builtin_amdgcn_mfma_f32_16x16x32_bf16(kb0, qa[0][0], z0, 0, 0, 0);        \
      z1 = __builtin_amdgcn_mfma_f32_16x16x32_bf16(kb0, qa[1][0], z1, 0, 0, 0);        \
      z0 = __builtin_amdgcn_mfma_f32_16x16x32_bf16(kb1, qa[0][1], z0, 0, 0, 0);        \
      z1 = __builtin_amdgcn_mfma_f32_16x16x32_bf16(kb1, qa[1][1], z1, 0, 0, 0);        \
      sc[0][nf] = z0; sc[1][nf] = z1;                                                  \
    }                                                                                  \
    __builtin_amdgcn_s_setprio(0);                                                     \
    _Pragma("unroll")                                                                  \
    for (int hf2 = 0; hf2 < 2; ++hf2) {                                                \
      unsigned long long mw = (hf2 == 0) ? mwh0 : mwh1;                                \
      unsigned nlo = ~(unsigned)mw;                                                    \
      unsigned nhi = ~(unsigned)(mw >> 32);                                            \
      float p[4][4];                                                                   \
      float rs = 0.f;                                                                  \
      _Pragma("unroll")                                                                \
      for (int nf = 0; nf < 4; ++nf) {                                                 \
        unsigned hfm = (nf < 2) ? nlo : nhi;                                           \
        _Pragma("unroll")                                                              \
        for (int r = 0; r < 4; ++r) {                                                  \
          float e = __builtin_amdgcn_exp2f(__builtin_fminf(sc[hf2][nf][r], 88.0f));    \
          int keep = ((int)(hfm << (31 - (16 * (nf & 1) + r)))) >> 31;                 \
          p[nf][r] = __uint_as_float(__float_as_uint(e) & (unsigned)keep);             \
        }                                                                              \
      }                                                                                \
      rs = ((p[0][0] + p[0][1]) + (p[0][2] + p[0][3])) +                               \
           ((p[1][0] + p[1][1]) + (p[1][2] + p[1][3])) +                               \
           ((p[2][0] + p[2][1]) + (p[2][2] + p[2][3])) +                               \
           ((p[3][0] + p[3][1]) + (p[3][2] + p[3][3]));                                \
      lrowp[hf2] += rs;                                                                \
      int rq = 16 * hf2 + lo;                                                          \
      _Pragma("unroll")                                                                \
      for (int nf = 0; nf < 4; ++nf) {                                                 \
        unsigned w0 = cvtpk(p[nf][0], p[nf][1]);                                       \
        unsigned w1 = cvtpk(p[nf][2], p[nf][3]);                                       \
        int dw = rq * 32 + ((8 * nf + 2 * hi) ^ ((lo & 7) << 2));                      \
        *(uint2*)(sPw + dw) = make_uint2(w0, w1);                                      \
      }                                                                                \
    }                                                                                  \
    __builtin_amdgcn_s_setprio(1);                                                     \
    _Pragma("unroll")                                                                  \
    for (int mh = 0; mh < 2; ++mh) {                                                   \
      bf16x8 pf0 = *(const bf16x8*)(sPw + (lo * 32 + ((16 * mh + 4 * hi) ^ ((lo & 7) << 2)))); \
      bf16x8 pf1 = *(const bf16x8*)(sPw + ((16 + lo) * 32 + ((16 * mh + 4 * hi) ^ ((lo & 7) << 2)))); \
      _Pragma("unroll")                                                                \
      for (int nd = 0; nd < 4; ++nd) {                                                 \
        int d = 16 * nd + lo;                                                          \
        bf16x8 vb = *(const bf16x8*)(sV[(CUR)] + d * 128 + (((4 * mh + hi) ^ (d & 7)) * 16)); \
        acc[0][nd] = __builtin_amdgcn_mfma_f32_16x16x32_bf16(vb, pf0, acc[0][nd], 0, 0, 0); \
        acc[1][nd] = __builtin_amdgcn_mfma_f32_16x16x32_bf16(vb, pf1, acc[1][nd], 0, 0, 0); \
      }                                                                                \
    }                                                                                  \
    __builtin_amdgcn_s_setprio(0);                                                     \
    __builtin_amdgcn_sched_barrier(0);                                                 \
    __builtin_amdgcn_s_barrier();                                                      \
  }

  for (int kt2 = 0; kt2 < NT_ / 2; ++kt2) {
    ATTN_STEP(0, 2 * kt2);
    ATTN_STEP(1, 2 * kt2 + 1);
  }
#undef ATTN_STEP

#pragma unroll
  for (int hf = 0; hf < 2; ++hf) {
    float lr = lrowp[hf];
    lr += __shfl_xor(lr, 16);
    lr += __shfl_xor(lr, 32);
    float inv = lr > 0.f ? 1.f / lr : 0.f;
    u16* crow = CTX + ((size_t)b * S_ + q0 + 32 * wv + 16 * hf + lo) * D_ + h * 64;
#pragma unroll
    for (int nd = 0; nd < 4; ++nd) {
      unsigned w0 = (unsigned)f2bf(acc[hf][nd][0] * inv) | ((unsigned)f2bf(acc[hf][nd][1] * inv) << 16);
      unsigned w1 = (unsigned)f2bf(acc[hf][nd][2] * inv) | ((unsigned)f2bf(acc[hf][nd][3] * inv) << 16);
      *(uint2*)(crow + 16 * nd + 4 * hi) = make_uint2(w0, w1);
    }
  }
}

// ---------------- launch ----------------
extern "C" void kernel_launch(void* const* d_in, const int* in_sizes, int n_in,
                              void* d_out, int out_size, void* d_ws, size_t ws_size,
                              hipStream_t stream) {
  const float* key   = (const float*)d_in[0];
  const float* value = (const float*)d_in[1];
  const float* query = (const float*)d_in[2];
  const void*  mask  = d_in[3];
  const float* Wq = (const float*)d_in[4];
  const float* bq = (const float*)d_in[5];
  const float* Wk = (const float*)d_in[6];
  const float* bk = (const float*)d_in[7];
  const float* Wv = (const float*)d_in[8];
  const float* bv = (const float*)d_in[9];
  const float* Wo = (const float*)d_in[10];
  const float* bo = (const float*)d_in[11];

  u16* Qb  = (u16*)d_ws;                 // Q proj (bf16), later ctx (safe alias)
  u16* Kb  = Qb + NE;
  u16* VTb = Kb + NE;                    // V stored [b][h][dn][s]
  u16* WT  = VTb + NE;                   // 4 transposed bf16 weights
  unsigned long long* M1 = (unsigned long long*)(WT + 4 * DD);
  unsigned int* flags = (unsigned int*)(M1 + (size_t)B_ * S_ * NT_);

  hipMemsetAsync(flags, 0, 8, stream);
  detect_mask_fmt<<<128, 256, 0, stream>>>((const uint4*)mask, flags);
  prep_bits<<<512, 256, 0, stream>>>(mask, flags, M1);
  cvt_w<<<2048, 256, 0, stream>>>(Wq, Wk, Wv, Wo, WT);

  const float QSCALE = 0.125f * 1.4426950408889634f;   // 1/sqrt(64) * log2(e)
  GArgs g3;
  g3.A[0] = query; g3.W[0] = WT + 0 * DD; g3.bias[0] = bq; g3.C[0] = Qb;  g3.scale[0] = QSCALE; g3.mode[0] = 0;
  g3.A[1] = key;   g3.W[1] = WT + 1 * DD; g3.bias[1] = bk; g3.C[1] = Kb;  g3.scale[1] = 1.f;    g3.mode[1] = 0;
  g3.A[2] = value; g3.W[2] = WT + 2 * DD; g3.bias[2] = bv; g3.C[2] = VTb; g3.scale[2] = 1.f;    g3.mode[2] = 2;
  gemm_bf16<1><<<dim3(D_ / 128, (B_ * S_) / 128, 3), 256, 0, stream>>>(g3);

  attn_mfma3<<<dim3(S_ / 128, B_ * H_), 256, 0, stream>>>(Qb, Kb, VTb, M1, Qb);

  GArgs go;
  go.A[0] = Qb; go.W[0] = WT + 3 * DD; go.bias[0] = bo; go.C[0] = d_out; go.scale[0] = 1.f; go.mode[0] = 1;
  go.A[1] = Qb; go.W[1] = WT + 3 * DD; go.bias[1] = bo; go.C[1] = d_out; go.scale[1] = 1.f; go.mode[1] = 1;
  go.A[2] = Qb; go.W[2] = WT + 3 * DD; go.bias[2] = bo; go.C[2] = d_out; go.scale[2] = 1.f; go.mode[2] = 1;
  gemm_bf16<0><<<dim3(D_ / 128, (B_ * S_) / 128, 1), 256, 0, stream>>>(go);
}

// Round 8
// 282.567 us; speedup vs baseline: 1.0671x; 1.0671x over previous
//
#include <hip/hip_runtime.h>
#include <hip/hip_bf16.h>
#include <cstdint>

#define B_   2
#define S_   2048
#define D_   1024
#define H_   16
#define DPH_ 64
#define NT_  (S_ / 64)

typedef float f32x4 __attribute__((ext_vector_type(4)));
typedef short bf16x8 __attribute__((ext_vector_type(8)));
typedef unsigned short u16;

static const size_t NE = (size_t)B_ * S_ * D_;   // 4,194,304 elements
static const size_t DD = (size_t)D_ * D_;

__device__ __forceinline__ u16 f2bf(float f) {
  union { float f; unsigned u; } cv; cv.f = f;
  unsigned u = cv.u;
  return (u16)((u + 0x7fffu + ((u >> 16) & 1u)) >> 16);
}

__device__ __forceinline__ unsigned cvtpk(float a, float b) {
  unsigned r;
  asm("v_cvt_pk_bf16_f32 %0, %1, %2" : "=v"(r) : "v"(a), "v"(b));
  return r;
}

__device__ __forceinline__ void gld16(const void* g, void* l) {
  __builtin_amdgcn_global_load_lds((const __attribute__((address_space(1))) unsigned int*)g,
                                   (__attribute__((address_space(3))) unsigned int*)l, 16, 0, 0);
}

// ---------------- mask format detection (512KB scan, wave-reduced, plain stores) ----------------
__global__ __launch_bounds__(256) void detect_mask_fmt(const uint4* __restrict__ m,
                                                       unsigned int* __restrict__ flags) {
  int i = blockIdx.x * 256 + threadIdx.x;
  uint4 v = m[i];
  int a = (v.x > 1u) | (v.y > 1u) | (v.z > 1u) | (v.w > 1u);
  int bb = ((v.x != 0u && v.x != 0x3f800000u) | (v.y != 0u && v.y != 0x3f800000u) |
            (v.z != 0u && v.z != 0x3f800000u) | (v.w != 0u && v.w != 0x3f800000u));
  int anyA = __any(a), anyB = __any(bb);
  if ((threadIdx.x & 63) == 0) {
    if (anyA) flags[0] = 1u;
    if (anyB) flags[1] = 1u;
  }
}

// ---------------- mask -> bitmask: M1[b][q][w] u64, bit k = disallowed ----------------
__device__ __forceinline__ unsigned nz4(unsigned w) {
  unsigned r = 0;
  if (w & 0x000000ffu) r |= 1u;
  if (w & 0x0000ff00u) r |= 2u;
  if (w & 0x00ff0000u) r |= 4u;
  if (w & 0xff000000u) r |= 8u;
  return r;
}

__global__ __launch_bounds__(256) void prep_bits(const void* __restrict__ src,
                                                 const unsigned int* __restrict__ flags,
                                                 unsigned long long* __restrict__ dst) {
  int i = blockIdx.x * 256 + threadIdx.x;
  unsigned long long w = 0;
  bool fourB = (flags[0] == 0u) || (flags[1] == 0u);
  if (fourB) {
    const uint4* p = (const uint4*)src + (size_t)i * 16;
#pragma unroll
    for (int j = 0; j < 16; ++j) {
      uint4 v = p[j];
      unsigned bits = (v.x ? 1u : 0u) | (v.y ? 2u : 0u) | (v.z ? 4u : 0u) | (v.w ? 8u : 0u);
      w |= (unsigned long long)bits << (j * 4);
    }
  } else {
    const uint4* p = (const uint4*)src + (size_t)i * 4;
#pragma unroll
    for (int j = 0; j < 4; ++j) {
      uint4 v = p[j];
      w |= (unsigned long long)nz4(v.x) << (j * 16 + 0);
      w |= (unsigned long long)nz4(v.y) << (j * 16 + 4);
      w |= (unsigned long long)nz4(v.z) << (j * 16 + 8);
      w |= (unsigned long long)nz4(v.w) << (j * 16 + 12);
    }
  }
  dst[i] = w;
}

// ---------------- weight transpose + convert: WT[n][k] = bf16(W[k][n]) ----------------
__global__ __launch_bounds__(256) void cvt_w(const float* __restrict__ Wq, const float* __restrict__ Wk,
                                             const float* __restrict__ Wv, const float* __restrict__ Wo,
                                             u16* __restrict__ WT) {
  int idx2 = blockIdx.x;                        // [0,2048)
  int mat = idx2 >> 9;
  const float* W = (mat == 0) ? Wq : (mat == 1) ? Wk : (mat == 2) ? Wv : Wo;
  u16* O = WT + (size_t)mat * DD;
  int t = (idx2 & 511) * 256 + threadIdx.x;     // [0,131072)
  int n = t & 1023, k8 = (t >> 10) << 3;
  bf16x8 o;
#pragma unroll
  for (int j = 0; j < 8; ++j) o[j] = (short)f2bf(W[(size_t)(k8 + j) * D_ + n]);
  *(bf16x8*)(O + (size_t)n * D_ + k8) = o;
}

// ---------------- bf16 MFMA GEMM: C = scale*(A @ WT^T + bias) ----------------
// Grid: x = m-tile (A panels distinct per block -> fetched once), y = n-tile (weight L2-shared).
// AF32=1: A is f32 (in-register cvt to bf16); AF32=0: A is bf16.
// mode 0: bf16 out; 1: f32 out; 2: bf16 VT[b][h][dn][s] via LDS transpose.
struct GArgs {
  const void* A[3]; const u16* W[3]; const float* bias[3];
  void* C[3]; float scale[3]; int mode[3];
};

template <int AF32>
__global__ __launch_bounds__(256, 3) void gemm_bf16(GArgs ga) {
  __shared__ unsigned char smem[49152];
  constexpr int ABUF = AF32 ? 16384 : 8192;     // per-buffer A bytes
  const int z = blockIdx.z;
  const u16* WT = ga.W[z]; const float* bias = ga.bias[z];
  void* Cout = ga.C[z]; const float scale = ga.scale[z]; const int mode = ga.mode[z];

  const int tid = threadIdx.x, wv = tid >> 6, lane = tid & 63;
  const int hi = lane >> 4, lo = lane & 15;
  const int wm = wv >> 1, wn = wv & 1;
  const int m0 = blockIdx.x * 128, n0 = blockIdx.y * 128;
  const char* ag = (const char*)ga.A[z] + (size_t)m0 * (AF32 ? 4096 : 2048);
  const char* bg = (const char*)WT + (size_t)n0 * 2048;
  unsigned char* sB0 = smem + 2 * ABUF;

  f32x4 acc[4][4];
#pragma unroll
  for (int i = 0; i < 4; ++i)
#pragma unroll
    for (int j = 0; j < 4; ++j) acc[i][j] = (f32x4){0.f, 0.f, 0.f, 0.f};

  auto stageA = [&](unsigned char* dst, int kt) {
    if constexpr (AF32) {
#pragma unroll
      for (int p = 0; p < 4; ++p) {
        int cid = p * 4 + wv;
        int slot = cid * 64 + lane;
        int r = slot >> 3, c = slot & 7;
        gld16(ag + (size_t)r * 4096 + kt * 128 + ((c ^ (r & 7)) * 16), dst + cid * 1024);
      }
    } else {
#pragma unroll
      for (int p = 0; p < 2; ++p) {
        int cid = p * 4 + wv;
        int slot = cid * 64 + lane;
        int r = slot >> 2, c = slot & 3;
        gld16(ag + (size_t)r * 2048 + kt * 64 + ((c ^ (r & 3)) * 16), dst + cid * 1024);
      }
    }
  };
  auto stageB = [&](unsigned char* dst, int kt) {
#pragma unroll
    for (int p = 0; p < 2; ++p) {
      int cid = p * 4 + wv;
      int slot = cid * 64 + lane;
      int r = slot >> 2, c = slot & 3;
      gld16(bg + (size_t)r * 2048 + kt * 64 + ((c ^ (r & 3)) * 16), dst + cid * 1024);
    }
  };

  stageA(smem, 0);
  stageB(sB0, 0);

  for (int kt = 0; kt < 32; ++kt) {
    int cur = kt & 1;
    unsigned char* sA = smem + cur * ABUF;
    unsigned char* sB = sB0 + cur * 8192;
    if (kt < 31) {
      stageA(smem + (cur ^ 1) * ABUF, kt + 1);
      stageB(sB0 + (cur ^ 1) * 8192, kt + 1);
      if constexpr (AF32) asm volatile("s_waitcnt vmcnt(6)" ::: "memory");
      else                asm volatile("s_waitcnt vmcnt(4)" ::: "memory");
    } else {
      asm volatile("s_waitcnt vmcnt(0)" ::: "memory");
    }
    __builtin_amdgcn_s_barrier();
    __builtin_amdgcn_sched_barrier(0);

    bf16x8 af[4], bf[4];
#pragma unroll
    for (int i = 0; i < 4; ++i) {
      int mr = 64 * wm + 16 * i + lo;
      if constexpr (AF32) {
        int s7 = mr & 7;
        f32x4 A0 = *(const f32x4*)(sA + mr * 128 + (((2 * hi) ^ s7) * 16));
        f32x4 A1 = *(const f32x4*)(sA + mr * 128 + (((2 * hi + 1) ^ s7) * 16));
        union { uint4 u; bf16x8 v; } cvu;
        cvu.u = make_uint4(cvtpk(A0[0], A0[1]), cvtpk(A0[2], A0[3]),
                           cvtpk(A1[0], A1[1]), cvtpk(A1[2], A1[3]));
        af[i] = cvu.v;
      } else {
        af[i] = *(const bf16x8*)(sA + mr * 64 + ((hi ^ (mr & 3)) * 16));
      }
      int nr = 64 * wn + 16 * i + lo;
      bf[i] = *(const bf16x8*)(sB + nr * 64 + ((hi ^ (nr & 3)) * 16));
    }
#pragma unroll
    for (int i = 0; i < 4; ++i)
#pragma unroll
      for (int j = 0; j < 4; ++j)
        acc[i][j] = __builtin_amdgcn_mfma_f32_16x16x32_bf16(af[i], bf[j], acc[i][j], 0, 0, 0);

    __builtin_amdgcn_sched_barrier(0);
    __builtin_amdgcn_s_barrier();
  }

  float bv[4];
#pragma unroll
  for (int j = 0; j < 4; ++j) bv[j] = bias[n0 + 64 * wn + 16 * j + lo];

  if (mode <= 1) {
#pragma unroll
    for (int i = 0; i < 4; ++i)
#pragma unroll
      for (int r = 0; r < 4; ++r) {
        int m = m0 + 64 * wm + 16 * i + 4 * hi + r;
#pragma unroll
        for (int j = 0; j < 4; ++j) {
          int n = n0 + 64 * wn + 16 * j + lo;
          float val = (acc[i][j][r] + bv[j]) * scale;
          if (mode == 0) ((u16*)Cout)[(size_t)m * D_ + n] = f2bf(val);
          else           ((float*)Cout)[(size_t)m * D_ + n] = val;
        }
      }
  } else {
    // V: transpose 128x128 tile through LDS, write VT[b][h][dn][s] coalesced
    __syncthreads();
#pragma unroll
    for (int i = 0; i < 4; ++i) {
      int mb2 = 64 * wm + 16 * i + 4 * hi;
#pragma unroll
      for (int j = 0; j < 4; ++j) {
        int n = 64 * wn + 16 * j + lo;
        unsigned w0 = (unsigned)f2bf(acc[i][j][0] + bv[j]) | ((unsigned)f2bf(acc[i][j][1] + bv[j]) << 16);
        unsigned w1 = (unsigned)f2bf(acc[i][j][2] + bv[j]) | ((unsigned)f2bf(acc[i][j][3] + bv[j]) << 16);
        unsigned byteoff = n * 256 + ((2 * mb2) ^ ((n & 7) << 5));
        *(uint2*)(smem + byteoff) = make_uint2(w0, w1);
      }
    }
    __syncthreads();
    int nl = tid >> 1, half = tid & 1;
    unsigned ob[32];
#pragma unroll
    for (int s = 0; s < 16; ++s) {
      unsigned byteoff = nl * 256 + ((128 * half + 8 * s) ^ ((nl & 7) << 5));
      uint2 vv = *(const uint2*)(smem + byteoff);
      ob[2 * s] = vv.x; ob[2 * s + 1] = vv.y;
    }
    int bb = blockIdx.x >> 4;                   // m-tile -> batch
    int habs = blockIdx.y * 2 + (nl >> 6);      // n-tile -> head pair
    int dn = nl & 63;
    size_t sg = (size_t)(blockIdx.x & 15) * 128 + half * 64;
    u16* outp = (u16*)Cout + ((size_t)(bb * H_ + habs) * 64 + dn) * 2048 + sg;
#pragma unroll
    for (int c2 = 0; c2 < 8; ++c2)
      *(uint4*)(outp + c2 * 8) = *(uint4*)&ob[4 * c2];
  }
}

// ---------------- MFMA flash attention: 64 q-rows, 4 blocks/CU, max-free softmax ----------------
// 4 waves x 16 q-rows. scores via mfma(K,Q): lane owns q-row (q0+16wv+lo).
// softmax: p = exp2(min(sc,88)) (shift-invariant, clamp prevents overflow); l-reduce deferred.
// PV via mfma(V^T,P): acc is ctx^T (d per reg, q per lane). CTX may alias Qb.
__global__ __launch_bounds__(256, 4) void attn_mfma4(const u16* __restrict__ Qb,
                                                     const u16* __restrict__ Kb,
                                                     const u16* __restrict__ VT,
                                                     const unsigned long long* __restrict__ M1,
                                                     u16* __restrict__ CTX) {
  __shared__ unsigned char sK[2][8192];
  __shared__ unsigned char sV[2][8192];
  __shared__ unsigned char sP[4][2048];        // per-wave pair-major P (16q x 64k), swizzled
  const int tid = threadIdx.x, wv = tid >> 6, lane = tid & 63;
  const int hi = lane >> 4, lo = lane & 15;
  const int b = blockIdx.y >> 4, h = blockIdx.y & (H_ - 1);
  const int q0 = blockIdx.x * 64;
  const char* kg = (const char*)(Kb + (size_t)b * S_ * D_ + h * 64);
  const char* vg = (const char*)(VT + ((size_t)(b * H_ + h) * 64) * S_);
  unsigned* sPw = (unsigned*)sP[wv];

  const u16* qr0 = Qb + ((size_t)b * S_ + q0 + 16 * wv + lo) * D_ + h * 64;
  bf16x8 qa0 = *(const bf16x8*)(qr0 + 8 * hi);
  bf16x8 qa1 = *(const bf16x8*)(qr0 + 32 + 8 * hi);

  auto stage8 = [&](unsigned char* dst, const char* srcbase, size_t rs) {
#pragma unroll
    for (int p = 0; p < 2; ++p) {
      int cid = p * 4 + wv;
      int slot = cid * 64 + lane;
      int r = slot >> 3, c = slot & 7;
      gld16(srcbase + (size_t)r * rs + ((c ^ (r & 7)) * 16), dst + cid * 1024);
    }
  };

  stage8(sK[0], kg, 2048);
  stage8(sV[0], vg, 4096);

  f32x4 acc[4];
#pragma unroll
  for (int i = 0; i < 4; ++i) acc[i] = (f32x4){0.f, 0.f, 0.f, 0.f};
  float lrowp = 0.f;                            // per-lane partial denominator
  const unsigned long long* mrp = M1 + ((size_t)b * S_ + q0 + 16 * wv + lo) * NT_;

#define ATTN_STEP(CUR, KT)                                                             \
  {                                                                                    \
    if ((KT) < NT_ - 1) {                                                              \
      stage8(sK[(CUR) ^ 1], kg + (size_t)((KT) + 1) * 64 * 2048, 2048);                \
      stage8(sV[(CUR) ^ 1], vg + (size_t)((KT) + 1) * 128, 4096);                      \
      asm volatile("s_waitcnt vmcnt(4)" ::: "memory");                                 \
    } else {                                                                           \
      asm volatile("s_waitcnt vmcnt(0)" ::: "memory");                                 \
    }                                                                                  \
    __builtin_amdgcn_s_barrier();                                                      \
    __builtin_amdgcn_sched_barrier(0);                                                 \
    unsigned long long mw = mrp[(KT)] >> (unsigned)(4 * hi);                           \
    f32x4 sc[4];                                                                       \
    __builtin_amdgcn_s_setprio(1);                                                     \
    _Pragma("unroll")                                                                  \
    for (int nf = 0; nf < 4; ++nf) {                                                   \
      int key = 16 * nf + lo;                                                          \
      bf16x8 kb0 = *(const bf16x8*)(sK[(CUR)] + key * 128 + (((0 + hi) ^ (key & 7)) * 16)); \
      bf16x8 kb1 = *(const bf16x8*)(sK[(CUR)] + key * 128 + (((4 + hi) ^ (key & 7)) * 16)); \
      f32x4 z = (f32x4){0.f, 0.f, 0.f, 0.f};                                           \
      z = __builtin_amdgcn_mfma_f32_16x16x32_bf16(kb0, qa0, z, 0, 0, 0);               \
      z = __builtin_amdgcn_mfma_f32_16x16x32_bf16(kb1, qa1, z, 0, 0, 0);               \
      sc[nf] = z;                                                                      \
    }                                                                                  \
    __builtin_amdgcn_s_setprio(0);                                                     \
    unsigned nlo = ~(unsigned)mw;                                                      \
    unsigned nhi = ~(unsigned)(mw >> 32);                                              \
    float p[4][4];                                                                     \
    _Pragma("unroll")                                                                  \
    for (int nf = 0; nf < 4; ++nf) {                                                   \
      unsigned hfm = (nf < 2) ? nlo : nhi;                                             \
      _Pragma("unroll")                                                                \
      for (int r = 0; r < 4; ++r) {                                                    \
        float e = __builtin_amdgcn_exp2f(__builtin_fminf(sc[nf][r], 88.0f));           \
        int keep = ((int)(hfm << (31 - (16 * (nf & 1) + r)))) >> 31;                   \
        p[nf][r] = __uint_as_float(__float_as_uint(e) & (unsigned)keep);               \
      }                                                                                \
    }                                                                                  \
    lrowp += ((p[0][0] + p[0][1]) + (p[0][2] + p[0][3])) +                             \
             ((p[1][0] + p[1][1]) + (p[1][2] + p[1][3])) +                             \
             ((p[2][0] + p[2][1]) + (p[2][2] + p[2][3])) +                             \
             ((p[3][0] + p[3][1]) + (p[3][2] + p[3][3]));                              \
    _Pragma("unroll")                                                                  \
    for (int nf = 0; nf < 4; ++nf) {                                                   \
      unsigned w0 = cvtpk(p[nf][0], p[nf][1]);                                         \
      unsigned w1 = cvtpk(p[nf][2], p[nf][3]);                                         \
      int dw = lo * 32 + ((8 * nf + 2 * hi) ^ ((lo & 7) << 2));                        \
      *(uint2*)(sPw + dw) = make_uint2(w0, w1);                                        \
    }                                                                                  \
    __builtin_amdgcn_s_setprio(1);                                                     \
    _Pragma("unroll")                                                                  \
    for (int mh = 0; mh < 2; ++mh) {                                                   \
      bf16x8 pf = *(const bf16x8*)(sPw + (lo * 32 + ((16 * mh + 4 * hi) ^ ((lo & 7) << 2)))); \
      _Pragma("unroll")                                                                \
      for (int nd = 0; nd < 4; ++nd) {                                                 \
        int d = 16 * nd + lo;                                                          \
        bf16x8 vb = *(const bf16x8*)(sV[(CUR)] + d * 128 + (((4 * mh + hi) ^ (d & 7)) * 16)); \
        acc[nd] = __builtin_amdgcn_mfma_f32_16x16x32_bf16(vb, pf, acc[nd], 0, 0, 0);   \
      }                                                                                \
    }                                                                                  \
    __builtin_amdgcn_s_setprio(0);                                                     \
    __builtin_amdgcn_sched_barrier(0);                                                 \
    __builtin_amdgcn_s_barrier();                                                      \
  }

  for (int kt2 = 0; kt2 < NT_ / 2; ++kt2) {
    ATTN_STEP(0, 2 * kt2);
    ATTN_STEP(1, 2 * kt2 + 1);
  }
#undef ATTN_STEP

  float lr = lrowp;
  lr += __shfl_xor(lr, 16);
  lr += __shfl_xor(lr, 32);
  float inv = lr > 0.f ? 1.f / lr : 0.f;
  u16* crow = CTX + ((size_t)b * S_ + q0 + 16 * wv + lo) * D_ + h * 64;
#pragma unroll
  for (int nd = 0; nd < 4; ++nd) {
    unsigned w0 = (unsigned)f2bf(acc[nd][0] * inv) | ((unsigned)f2bf(acc[nd][1] * inv) << 16);
    unsigned w1 = (unsigned)f2bf(acc[nd][2] * inv) | ((unsigned)f2bf(acc[nd][3] * inv) << 16);
    *(uint2*)(crow + 16 * nd + 4 * hi) = make_uint2(w0, w1);
  }
}

// ---------------- launch ----------------
extern "C" void kernel_launch(void* const* d_in, const int* in_sizes, int n_in,
                              void* d_out, int out_size, void* d_ws, size_t ws_size,
                              hipStream_t stream) {
  const float* key   = (const float*)d_in[0];
  const float* value = (const float*)d_in[1];
  const float* query = (const float*)d_in[2];
  const void*  mask  = d_in[3];
  const float* Wq = (const float*)d_in[4];
  const float* bq = (const float*)d_in[5];
  const float* Wk = (const float*)d_in[6];
  const float* bk = (const float*)d_in[7];
  const float* Wv = (const float*)d_in[8];
  const float* bv = (const float*)d_in[9];
  const float* Wo = (const float*)d_in[10];
  const float* bo = (const float*)d_in[11];

  u16* Qb  = (u16*)d_ws;                 // Q proj (bf16), later ctx (safe alias)
  u16* Kb  = Qb + NE;
  u16* VTb = Kb + NE;                    // V stored [b][h][dn][s]
  u16* WT  = VTb + NE;                   // 4 transposed bf16 weights
  unsigned long long* M1 = (unsigned long long*)(WT + 4 * DD);
  unsigned int* flags = (unsigned int*)(M1 + (size_t)B_ * S_ * NT_);

  hipMemsetAsync(flags, 0, 8, stream);
  detect_mask_fmt<<<128, 256, 0, stream>>>((const uint4*)mask, flags);
  prep_bits<<<512, 256, 0, stream>>>(mask, flags, M1);
  cvt_w<<<2048, 256, 0, stream>>>(Wq, Wk, Wv, Wo, WT);

  const float QSCALE = 0.125f * 1.4426950408889634f;   // 1/sqrt(64) * log2(e)
  GArgs g3;
  g3.A[0] = query; g3.W[0] = WT + 0 * DD; g3.bias[0] = bq; g3.C[0] = Qb;  g3.scale[0] = QSCALE; g3.mode[0] = 0;
  g3.A[1] = key;   g3.W[1] = WT + 1 * DD; g3.bias[1] = bk; g3.C[1] = Kb;  g3.scale[1] = 1.f;    g3.mode[1] = 0;
  g3.A[2] = value; g3.W[2] = WT + 2 * DD; g3.bias[2] = bv; g3.C[2] = VTb; g3.scale[2] = 1.f;    g3.mode[2] = 2;
  gemm_bf16<1><<<dim3((B_ * S_) / 128, D_ / 128, 3), 256, 0, stream>>>(g3);

  attn_mfma4<<<dim3(S_ / 64, B_ * H_), 256, 0, stream>>>(Qb, Kb, VTb, M1, Qb);

  GArgs go;
  go.A[0] = Qb; go.W[0] = WT + 3 * DD; go.bias[0] = bo; go.C[0] = d_out; go.scale[0] = 1.f; go.mode[0] = 1;
  go.A[1] = Qb; go.W[1] = WT + 3 * DD; go.bias[1] = bo; go.C[1] = d_out; go.scale[1] = 1.f; go.mode[1] = 1;
  go.A[2] = Qb; go.W[2] = WT + 3 * DD; go.bias[2] = bo; go.C[2] = d_out; go.scale[2] = 1.f; go.mode[2] = 1;
  gemm_bf16<0><<<dim3((B_ * S_) / 128, D_ / 128, 1), 256, 0, stream>>>(go);
}

// Round 9
// 282.351 us; speedup vs baseline: 1.0679x; 1.0008x over previous
//
#include <hip/hip_runtime.h>
#include <hip/hip_bf16.h>
#include <cstdint>

#define B_   2
#define S_   2048
#define D_   1024
#define H_   16
#define DPH_ 64
#define NT_  (S_ / 64)

typedef float f32x4 __attribute__((ext_vector_type(4)));
typedef short bf16x8 __attribute__((ext_vector_type(8)));
typedef short bf16x4 __attribute__((ext_vector_type(4)));
typedef unsigned short u16;

static const size_t NE = (size_t)B_ * S_ * D_;   // 4,194,304 elements
static const size_t DD = (size_t)D_ * D_;

__device__ __forceinline__ u16 f2bf(float f) {
  union { float f; unsigned u; } cv; cv.f = f;
  unsigned u = cv.u;
  return (u16)((u + 0x7fffu + ((u >> 16) & 1u)) >> 16);
}

__device__ __forceinline__ unsigned cvtpk(float a, float b) {
  unsigned r;
  asm("v_cvt_pk_bf16_f32 %0, %1, %2" : "=v"(r) : "v"(a), "v"(b));
  return r;
}

__device__ __forceinline__ void gld16(const void* g, void* l) {
  __builtin_amdgcn_global_load_lds((const __attribute__((address_space(1))) unsigned int*)g,
                                   (__attribute__((address_space(3))) unsigned int*)l, 16, 0, 0);
}

// ---------------- mask format detection (512KB scan, wave-reduced, plain stores) ----------------
__global__ __launch_bounds__(256) void detect_mask_fmt(const uint4* __restrict__ m,
                                                       unsigned int* __restrict__ flags) {
  int i = blockIdx.x * 256 + threadIdx.x;
  uint4 v = m[i];
  int a = (v.x > 1u) | (v.y > 1u) | (v.z > 1u) | (v.w > 1u);
  int bb = ((v.x != 0u && v.x != 0x3f800000u) | (v.y != 0u && v.y != 0x3f800000u) |
            (v.z != 0u && v.z != 0x3f800000u) | (v.w != 0u && v.w != 0x3f800000u));
  int anyA = __any(a), anyB = __any(bb);
  if ((threadIdx.x & 63) == 0) {
    if (anyA) flags[0] = 1u;
    if (anyB) flags[1] = 1u;
  }
}

// ---------------- mask -> bitmask: M1[b][q][w] u64, bit k = disallowed ----------------
__device__ __forceinline__ unsigned nz4(unsigned w) {
  unsigned r = 0;
  if (w & 0x000000ffu) r |= 1u;
  if (w & 0x0000ff00u) r |= 2u;
  if (w & 0x00ff0000u) r |= 4u;
  if (w & 0xff000000u) r |= 8u;
  return r;
}

__global__ __launch_bounds__(256) void prep_bits(const void* __restrict__ src,
                                                 const unsigned int* __restrict__ flags,
                                                 unsigned long long* __restrict__ dst) {
  int i = blockIdx.x * 256 + threadIdx.x;
  unsigned long long w = 0;
  bool fourB = (flags[0] == 0u) || (flags[1] == 0u);
  if (fourB) {
    const uint4* p = (const uint4*)src + (size_t)i * 16;
#pragma unroll
    for (int j = 0; j < 16; ++j) {
      uint4 v = p[j];
      unsigned bits = (v.x ? 1u : 0u) | (v.y ? 2u : 0u) | (v.z ? 4u : 0u) | (v.w ? 8u : 0u);
      w |= (unsigned long long)bits << (j * 4);
    }
  } else {
    const uint4* p = (const uint4*)src + (size_t)i * 4;
#pragma unroll
    for (int j = 0; j < 4; ++j) {
      uint4 v = p[j];
      w |= (unsigned long long)nz4(v.x) << (j * 16 + 0);
      w |= (unsigned long long)nz4(v.y) << (j * 16 + 4);
      w |= (unsigned long long)nz4(v.z) << (j * 16 + 8);
      w |= (unsigned long long)nz4(v.w) << (j * 16 + 12);
    }
  }
  dst[i] = w;
}

// ---------------- weight transpose + convert: WT[n][k] = bf16(W[k][n]) ----------------
__global__ __launch_bounds__(256) void cvt_w(const float* __restrict__ Wq, const float* __restrict__ Wk,
                                             const float* __restrict__ Wv, const float* __restrict__ Wo,
                                             u16* __restrict__ WT) {
  int idx2 = blockIdx.x;                        // [0,2048)
  int mat = idx2 >> 9;
  const float* W = (mat == 0) ? Wq : (mat == 1) ? Wk : (mat == 2) ? Wv : Wo;
  u16* O = WT + (size_t)mat * DD;
  int t = (idx2 & 511) * 256 + threadIdx.x;     // [0,131072)
  int n = t & 1023, k8 = (t >> 10) << 3;
  bf16x8 o;
#pragma unroll
  for (int j = 0; j < 8; ++j) o[j] = (short)f2bf(W[(size_t)(k8 + j) * D_ + n]);
  *(bf16x8*)(O + (size_t)n * D_ + k8) = o;
}

// ---------------- bf16 MFMA GEMM: C = scale*(A @ WT^T + bias) ----------------
// Grid: x = m-tile (A panels distinct per block -> fetched once), y = n-tile (weight L2-shared).
// AF32=1: A is f32 (in-register cvt to bf16); AF32=0: A is bf16.
// mode 0: bf16 out; 1: f32 out; 2: bf16 VT[b][h][dn][s] via LDS transpose.
struct GArgs {
  const void* A[3]; const u16* W[3]; const float* bias[3];
  void* C[3]; float scale[3]; int mode[3];
};

template <int AF32>
__global__ __launch_bounds__(256, 3) void gemm_bf16(GArgs ga) {
  __shared__ unsigned char smem[49152];
  constexpr int ABUF = AF32 ? 16384 : 8192;     // per-buffer A bytes
  const int z = blockIdx.z;
  const u16* WT = ga.W[z]; const float* bias = ga.bias[z];
  void* Cout = ga.C[z]; const float scale = ga.scale[z]; const int mode = ga.mode[z];

  const int tid = threadIdx.x, wv = tid >> 6, lane = tid & 63;
  const int hi = lane >> 4, lo = lane & 15;
  const int wm = wv >> 1, wn = wv & 1;
  const int m0 = blockIdx.x * 128, n0 = blockIdx.y * 128;
  const char* ag = (const char*)ga.A[z] + (size_t)m0 * (AF32 ? 4096 : 2048);
  const char* bg = (const char*)WT + (size_t)n0 * 2048;
  unsigned char* sB0 = smem + 2 * ABUF;

  f32x4 acc[4][4];
#pragma unroll
  for (int i = 0; i < 4; ++i)
#pragma unroll
    for (int j = 0; j < 4; ++j) acc[i][j] = (f32x4){0.f, 0.f, 0.f, 0.f};

  auto stageA = [&](unsigned char* dst, int kt) {
    if constexpr (AF32) {
#pragma unroll
      for (int p = 0; p < 4; ++p) {
        int cid = p * 4 + wv;
        int slot = cid * 64 + lane;
        int r = slot >> 3, c = slot & 7;
        gld16(ag + (size_t)r * 4096 + kt * 128 + ((c ^ (r & 7)) * 16), dst + cid * 1024);
      }
    } else {
#pragma unroll
      for (int p = 0; p < 2; ++p) {
        int cid = p * 4 + wv;
        int slot = cid * 64 + lane;
        int r = slot >> 2, c = slot & 3;
        gld16(ag + (size_t)r * 2048 + kt * 64 + ((c ^ (r & 3)) * 16), dst + cid * 1024);
      }
    }
  };
  auto stageB = [&](unsigned char* dst, int kt) {
#pragma unroll
    for (int p = 0; p < 2; ++p) {
      int cid = p * 4 + wv;
      int slot = cid * 64 + lane;
      int r = slot >> 2, c = slot & 3;
      gld16(bg + (size_t)r * 2048 + kt * 64 + ((c ^ (r & 3)) * 16), dst + cid * 1024);
    }
  };

  stageA(smem, 0);
  stageB(sB0, 0);

  for (int kt = 0; kt < 32; ++kt) {
    int cur = kt & 1;
    unsigned char* sA = smem + cur * ABUF;
    unsigned char* sB = sB0 + cur * 8192;
    if (kt < 31) {
      stageA(smem + (cur ^ 1) * ABUF, kt + 1);
      stageB(sB0 + (cur ^ 1) * 8192, kt + 1);
      if constexpr (AF32) asm volatile("s_waitcnt vmcnt(6)" ::: "memory");
      else                asm volatile("s_waitcnt vmcnt(4)" ::: "memory");
    } else {
      asm volatile("s_waitcnt vmcnt(0)" ::: "memory");
    }
    __builtin_amdgcn_s_barrier();
    __builtin_amdgcn_sched_barrier(0);

    bf16x8 af[4], bf[4];
#pragma unroll
    for (int i = 0; i < 4; ++i) {
      int mr = 64 * wm + 16 * i + lo;
      if constexpr (AF32) {
        int s7 = mr & 7;
        f32x4 A0 = *(const f32x4*)(sA + mr * 128 + (((2 * hi) ^ s7) * 16));
        f32x4 A1 = *(const f32x4*)(sA + mr * 128 + (((2 * hi + 1) ^ s7) * 16));
        union { uint4 u; bf16x8 v; } cvu;
        cvu.u = make_uint4(cvtpk(A0[0], A0[1]), cvtpk(A0[2], A0[3]),
                           cvtpk(A1[0], A1[1]), cvtpk(A1[2], A1[3]));
        af[i] = cvu.v;
      } else {
        af[i] = *(const bf16x8*)(sA + mr * 64 + ((hi ^ (mr & 3)) * 16));
      }
      int nr = 64 * wn + 16 * i + lo;
      bf[i] = *(const bf16x8*)(sB + nr * 64 + ((hi ^ (nr & 3)) * 16));
    }
#pragma unroll
    for (int i = 0; i < 4; ++i)
#pragma unroll
      for (int j = 0; j < 4; ++j)
        acc[i][j] = __builtin_amdgcn_mfma_f32_16x16x32_bf16(af[i], bf[j], acc[i][j], 0, 0, 0);

    __builtin_amdgcn_sched_barrier(0);
    __builtin_amdgcn_s_barrier();
  }

  float bv[4];
#pragma unroll
  for (int j = 0; j < 4; ++j) bv[j] = bias[n0 + 64 * wn + 16 * j + lo];

  if (mode <= 1) {
#pragma unroll
    for (int i = 0; i < 4; ++i)
#pragma unroll
      for (int r = 0; r < 4; ++r) {
        int m = m0 + 64 * wm + 16 * i + 4 * hi + r;
#pragma unroll
        for (int j = 0; j < 4; ++j) {
          int n = n0 + 64 * wn + 16 * j + lo;
          float val = (acc[i][j][r] + bv[j]) * scale;
          if (mode == 0) ((u16*)Cout)[(size_t)m * D_ + n] = f2bf(val);
          else           ((float*)Cout)[(size_t)m * D_ + n] = val;
        }
      }
  } else {
    // V: transpose 128x128 tile through LDS, write VT[b][h][dn][s] coalesced
    __syncthreads();
#pragma unroll
    for (int i = 0; i < 4; ++i) {
      int mb2 = 64 * wm + 16 * i + 4 * hi;
#pragma unroll
      for (int j = 0; j < 4; ++j) {
        int n = 64 * wn + 16 * j + lo;
        unsigned w0 = (unsigned)f2bf(acc[i][j][0] + bv[j]) | ((unsigned)f2bf(acc[i][j][1] + bv[j]) << 16);
        unsigned w1 = (unsigned)f2bf(acc[i][j][2] + bv[j]) | ((unsigned)f2bf(acc[i][j][3] + bv[j]) << 16);
        unsigned byteoff = n * 256 + ((2 * mb2) ^ ((n & 7) << 5));
        *(uint2*)(smem + byteoff) = make_uint2(w0, w1);
      }
    }
    __syncthreads();
    int nl = tid >> 1, half = tid & 1;
    unsigned ob[32];
#pragma unroll
    for (int s = 0; s < 16; ++s) {
      unsigned byteoff = nl * 256 + ((128 * half + 8 * s) ^ ((nl & 7) << 5));
      uint2 vv = *(const uint2*)(smem + byteoff);
      ob[2 * s] = vv.x; ob[2 * s + 1] = vv.y;
    }
    int bb = blockIdx.x >> 4;                   // m-tile -> batch
    int habs = blockIdx.y * 2 + (nl >> 6);      // n-tile -> head pair
    int dn = nl & 63;
    size_t sg = (size_t)(blockIdx.x & 15) * 128 + half * 64;
    u16* outp = (u16*)Cout + ((size_t)(bb * H_ + habs) * 64 + dn) * 2048 + sg;
#pragma unroll
    for (int c2 = 0; c2 < 8; ++c2)
      *(uint4*)(outp + c2 * 8) = *(uint4*)&ob[4 * c2];
  }
}

// ---------------- MFMA flash attention: register P via K=16 PV, no sP ----------------
// 4 waves x 16 q-rows. QK^T swapped mfma(K,Q): lane(hi,lo) holds S[key=16nf+4hi+r][q=lo].
// That IS the B-fragment layout of mfma_f32_16x16x16bf16_1k (B[k=4hi+i][n=lo]) per key-group
// nf, so P never touches LDS: pfrag[nf] = 2x cvt_pk of p[nf][*]. PV: 16 K=16 MFMAs with
// V^T slices via ds_read_b64. C-layout (row=4hi+r=d_local, col=lo=q) unchanged.
__global__ __launch_bounds__(256, 4) void attn_mfma5(const u16* __restrict__ Qb,
                                                     const u16* __restrict__ Kb,
                                                     const u16* __restrict__ VT,
                                                     const unsigned long long* __restrict__ M1,
                                                     u16* __restrict__ CTX) {
  __shared__ unsigned char sK[2][8192];
  __shared__ unsigned char sV[2][8192];
  const int tid = threadIdx.x, wv = tid >> 6, lane = tid & 63;
  const int hi = lane >> 4, lo = lane & 15;
  const int b = blockIdx.y >> 4, h = blockIdx.y & (H_ - 1);
  const int q0 = blockIdx.x * 64;
  const char* kg = (const char*)(Kb + (size_t)b * S_ * D_ + h * 64);
  const char* vg = (const char*)(VT + ((size_t)(b * H_ + h) * 64) * S_);

  const u16* qr0 = Qb + ((size_t)b * S_ + q0 + 16 * wv + lo) * D_ + h * 64;
  bf16x8 qa0 = *(const bf16x8*)(qr0 + 8 * hi);
  bf16x8 qa1 = *(const bf16x8*)(qr0 + 32 + 8 * hi);

  auto stage8 = [&](unsigned char* dst, const char* srcbase, size_t rs) {
#pragma unroll
    for (int p = 0; p < 2; ++p) {
      int cid = p * 4 + wv;
      int slot = cid * 64 + lane;
      int r = slot >> 3, c = slot & 7;
      gld16(srcbase + (size_t)r * rs + ((c ^ (r & 7)) * 16), dst + cid * 1024);
    }
  };

  stage8(sK[0], kg, 2048);
  stage8(sV[0], vg, 4096);

  f32x4 acc[4];
#pragma unroll
  for (int i = 0; i < 4; ++i) acc[i] = (f32x4){0.f, 0.f, 0.f, 0.f};
  float lrowp = 0.f;                            // per-lane partial denominator
  const unsigned long long* mrp = M1 + ((size_t)b * S_ + q0 + 16 * wv + lo) * NT_;

#define ATTN_STEP(CUR, KT)                                                             \
  {                                                                                    \
    if ((KT) < NT_ - 1) {                                                              \
      stage8(sK[(CUR) ^ 1], kg + (size_t)((KT) + 1) * 64 * 2048, 2048);                \
      stage8(sV[(CUR) ^ 1], vg + (size_t)((KT) + 1) * 128, 4096);                      \
      asm volatile("s_waitcnt vmcnt(4)" ::: "memory");                                 \
    } else {                                                                           \
      asm volatile("s_waitcnt vmcnt(0)" ::: "memory");                                 \
    }                                                                                  \
    __builtin_amdgcn_s_barrier();                                                      \
    __builtin_amdgcn_sched_barrier(0);                                                 \
    unsigned long long mw = mrp[(KT)] >> (unsigned)(4 * hi);                           \
    f32x4 sc[4];                                                                       \
    __builtin_amdgcn_s_setprio(1);                                                     \
    _Pragma("unroll")                                                                  \
    for (int nf = 0; nf < 4; ++nf) {                                                   \
      int key = 16 * nf + lo;                                                          \
      bf16x8 kb0 = *(const bf16x8*)(sK[(CUR)] + key * 128 + (((0 + hi) ^ (key & 7)) * 16)); \
      bf16x8 kb1 = *(const bf16x8*)(sK[(CUR)] + key * 128 + (((4 + hi) ^ (key & 7)) * 16)); \
      f32x4 z = (f32x4){0.f, 0.f, 0.f, 0.f};                                           \
      z = __builtin_amdgcn_mfma_f32_16x16x32_bf16(kb0, qa0, z, 0, 0, 0);               \
      z = __builtin_amdgcn_mfma_f32_16x16x32_bf16(kb1, qa1, z, 0, 0, 0);               \
      sc[nf] = z;                                                                      \
    }                                                                                  \
    __builtin_amdgcn_s_setprio(0);                                                     \
    unsigned nlo = ~(unsigned)mw;                                                      \
    unsigned nhi = ~(unsigned)(mw >> 32);                                              \
    bf16x4 pa[4];                                                                      \
    _Pragma("unroll")                                                                  \
    for (int nf = 0; nf < 4; ++nf) {                                                   \
      unsigned hfm = (nf < 2) ? nlo : nhi;                                             \
      float p[4];                                                                      \
      _Pragma("unroll")                                                                \
      for (int r = 0; r < 4; ++r) {                                                    \
        float e = __builtin_amdgcn_exp2f(__builtin_fminf(sc[nf][r], 88.0f));           \
        int keep = ((int)(hfm << (31 - (16 * (nf & 1) + r)))) >> 31;                   \
        p[r] = __uint_as_float(__float_as_uint(e) & (unsigned)keep);                   \
      }                                                                                \
      lrowp += (p[0] + p[1]) + (p[2] + p[3]);                                          \
      union { uint2 u; bf16x4 v; } pu;                                                 \
      pu.u = make_uint2(cvtpk(p[0], p[1]), cvtpk(p[2], p[3]));                         \
      pa[nf] = pu.v;                                                                   \
    }                                                                                  \
    __builtin_amdgcn_s_setprio(1);                                                     \
    _Pragma("unroll")                                                                  \
    for (int nf = 0; nf < 4; ++nf) {                                                   \
      _Pragma("unroll")                                                                \
      for (int nd = 0; nd < 4; ++nd) {                                                 \
        bf16x4 vb = *(const bf16x4*)(sV[(CUR)] + (16 * nd + lo) * 128 +                \
                     (((2 * nf + (hi >> 1)) ^ (lo & 7)) * 16) + 8 * (hi & 1));         \
        acc[nd] = __builtin_amdgcn_mfma_f32_16x16x16bf16_1k(vb, pa[nf], acc[nd], 0, 0, 0); \
      }                                                                                \
    }                                                                                  \
    __builtin_amdgcn_s_setprio(0);                                                     \
    __builtin_amdgcn_sched_barrier(0);                                                 \
    __builtin_amdgcn_s_barrier();                                                      \
  }

  for (int kt2 = 0; kt2 < NT_ / 2; ++kt2) {
    ATTN_STEP(0, 2 * kt2);
    ATTN_STEP(1, 2 * kt2 + 1);
  }
#undef ATTN_STEP

  float lr = lrowp;
  lr += __shfl_xor(lr, 16);
  lr += __shfl_xor(lr, 32);
  float inv = lr > 0.f ? 1.f / lr : 0.f;
  u16* crow = CTX + ((size_t)b * S_ + q0 + 16 * wv + lo) * D_ + h * 64;
#pragma unroll
  for (int nd = 0; nd < 4; ++nd) {
    unsigned w0 = (unsigned)f2bf(acc[nd][0] * inv) | ((unsigned)f2bf(acc[nd][1] * inv) << 16);
    unsigned w1 = (unsigned)f2bf(acc[nd][2] * inv) | ((unsigned)f2bf(acc[nd][3] * inv) << 16);
    *(uint2*)(crow + 16 * nd + 4 * hi) = make_uint2(w0, w1);
  }
}

// ---------------- launch ----------------
extern "C" void kernel_launch(void* const* d_in, const int* in_sizes, int n_in,
                              void* d_out, int out_size, void* d_ws, size_t ws_size,
                              hipStream_t stream) {
  const float* key   = (const float*)d_in[0];
  const float* value = (const float*)d_in[1];
  const float* query = (const float*)d_in[2];
  const void*  mask  = d_in[3];
  const float* Wq = (const float*)d_in[4];
  const float* bq = (const float*)d_in[5];
  const float* Wk = (const float*)d_in[6];
  const float* bk = (const float*)d_in[7];
  const float* Wv = (const float*)d_in[8];
  const float* bv = (const float*)d_in[9];
  const float* Wo = (const float*)d_in[10];
  const float* bo = (const float*)d_in[11];

  u16* Qb  = (u16*)d_ws;                 // Q proj (bf16), later ctx (safe alias)
  u16* Kb  = Qb + NE;
  u16* VTb = Kb + NE;                    // V stored [b][h][dn][s]
  u16* WT  = VTb + NE;                   // 4 transposed bf16 weights
  unsigned long long* M1 = (unsigned long long*)(WT + 4 * DD);
  unsigned int* flags = (unsigned int*)(M1 + (size_t)B_ * S_ * NT_);

  hipMemsetAsync(flags, 0, 8, stream);
  detect_mask_fmt<<<128, 256, 0, stream>>>((const uint4*)mask, flags);
  prep_bits<<<512, 256, 0, stream>>>(mask, flags, M1);
  cvt_w<<<2048, 256, 0, stream>>>(Wq, Wk, Wv, Wo, WT);

  const float QSCALE = 0.125f * 1.4426950408889634f;   // 1/sqrt(64) * log2(e)
  GArgs g3;
  g3.A[0] = query; g3.W[0] = WT + 0 * DD; g3.bias[0] = bq; g3.C[0] = Qb;  g3.scale[0] = QSCALE; g3.mode[0] = 0;
  g3.A[1] = key;   g3.W[1] = WT + 1 * DD; g3.bias[1] = bk; g3.C[1] = Kb;  g3.scale[1] = 1.f;    g3.mode[1] = 0;
  g3.A[2] = value; g3.W[2] = WT + 2 * DD; g3.bias[2] = bv; g3.C[2] = VTb; g3.scale[2] = 1.f;    g3.mode[2] = 2;
  gemm_bf16<1><<<dim3((B_ * S_) / 128, D_ / 128, 3), 256, 0, stream>>>(g3);

  attn_mfma5<<<dim3(S_ / 64, B_ * H_), 256, 0, stream>>>(Qb, Kb, VTb, M1, Qb);

  GArgs go;
  go.A[0] = Qb; go.W[0] = WT + 3 * DD; go.bias[0] = bo; go.C[0] = d_out; go.scale[0] = 1.f; go.mode[0] = 1;
  go.A[1] = Qb; go.W[1] = WT + 3 * DD; go.bias[1] = bo; go.C[1] = d_out; go.scale[1] = 1.f; go.mode[1] = 1;
  go.A[2] = Qb; go.W[2] = WT + 3 * DD; go.bias[2] = bo; go.C[2] = d_out; go.scale[2] = 1.f; go.mode[2] = 1;
  gemm_bf16<0><<<dim3((B_ * S_) / 128, D_ / 128, 1), 256, 0, stream>>>(go);
}